// Round 4
// baseline (49.614 us; speedup 1.0000x reference)
//
#include <hip/hip_runtime.h>

#define DIM 64
#define NPB 512          // nodes per bucket (power of 2: bin = dst>>9)
#define CAP 32           // slots per (block,bin) segment (power of 2)
#define K2_THREADS 512
#define K2_U 8           // edges per thread in bin kernel
#define K2_EPB (K2_THREADS * K2_U)   // 4096 edges per block

// Kernel 1: 16 threads per node row, float4 loads.
// s[i]   = dot(x[i], W_rel)
// out[i] = dot(x[i], W_root) + b_rel   (full overwrite -> replay-safe)
__global__ void node_scores_kernel(const float4* __restrict__ x4,
                                   const float4* __restrict__ Wrel4,
                                   const float* __restrict__ b_rel,
                                   const float4* __restrict__ Wroot4,
                                   float* __restrict__ s,
                                   float* __restrict__ out,
                                   int n) {
    int tid = threadIdx.x;
    int node = blockIdx.x * 16 + (tid >> 4);
    int c = tid & 15;
    if (node >= n) return;

    float4 xv = x4[(size_t)node * (DIM / 4) + c];
    float4 wr = Wrel4[c];
    float4 wt = Wroot4[c];
    float sr = xv.x * wr.x + xv.y * wr.y + xv.z * wr.z + xv.w * wr.w;
    float st = xv.x * wt.x + xv.y * wt.y + xv.z * wt.z + xv.w * wt.w;

    #pragma unroll
    for (int off = 1; off < 16; off <<= 1) {
        sr += __shfl_xor(sr, off);
        st += __shfl_xor(st, off);
    }
    if (c == 0) {
        s[node]   = sr;
        out[node] = st + b_rel[0];
    }
}

// Kernel 2: bin edges by destination bucket.
// Block blk handles edges [blk*4096, ...+4096). For each edge: bin = dst>>9,
// rank via LDS histogram atomic, pair (dstLocal, sval) written to the fixed
// segment bucket[(bin*NBLK + blk)*CAP + rank]. cnt[bin*NBLK+blk] = min(hist,CAP).
// Rank overflow (rare) falls back to a global atomicAdd on out.
__global__ void bin_kernel(const int* __restrict__ ei,
                           const float* __restrict__ s,
                           float* __restrict__ out,
                           int* __restrict__ cnt,
                           int2* __restrict__ bucket,
                           int E, int NB, int NBLK) {
    extern __shared__ int hist[];   // NB ints
    int tid = threadIdx.x;
    int blk = blockIdx.x;

    for (int i = tid; i < NB; i += K2_THREADS) hist[i] = 0;
    __syncthreads();

    long base = (long)blk * K2_EPB + (long)tid * K2_U;
    int   dst[K2_U];
    float val[K2_U];
    int   rnk[K2_U];
    int   have = 0;

    if (base + K2_U <= E) {
        const int4* sv = (const int4*)ei;        // src row
        const int4* dv = (const int4*)(ei + E);  // dst row
        long g = base >> 2;
        int4 s0 = sv[g], s1 = sv[g + 1];
        int4 d0 = dv[g], d1 = dv[g + 1];
        dst[0] = d0.x; dst[1] = d0.y; dst[2] = d0.z; dst[3] = d0.w;
        dst[4] = d1.x; dst[5] = d1.y; dst[6] = d1.z; dst[7] = d1.w;
        val[0] = s[s0.x]; val[1] = s[s0.y]; val[2] = s[s0.z]; val[3] = s[s0.w];
        val[4] = s[s1.x]; val[5] = s[s1.y]; val[6] = s[s1.z]; val[7] = s[s1.w];
        have = K2_U;
    } else {
        #pragma unroll
        for (int k = 0; k < K2_U; ++k) {
            long e = base + k;
            if (e < E) {
                dst[k] = ei[E + e];
                val[k] = s[ei[e]];
                have = k + 1;
            }
        }
    }

    #pragma unroll
    for (int k = 0; k < K2_U; ++k)
        if (k < have) rnk[k] = atomicAdd(&hist[dst[k] >> 9], 1);
    __syncthreads();

    for (int b = tid; b < NB; b += K2_THREADS)
        cnt[(size_t)b * NBLK + blk] = min(hist[b], CAP);

    #pragma unroll
    for (int k = 0; k < K2_U; ++k) {
        if (k < have) {
            int bin = dst[k] >> 9;
            if (rnk[k] < CAP) {
                bucket[((size_t)bin * NBLK + blk) * CAP + rnk[k]] =
                    make_int2(dst[k] & (NPB - 1), __float_as_int(val[k]));
            } else {
                atomicAdd(&out[dst[k]], val[k]);
            }
        }
    }
}

// Kernel 3: one block per bucket. Read the bucket's contiguous strip,
// LDS-accumulate, then plain RMW of this bucket's out slice (disjoint).
__global__ void gather_kernel(const int* __restrict__ cnt,
                              const int2* __restrict__ bucket,
                              float* __restrict__ out,
                              int n, int NBLK) {
    extern __shared__ float smem[];
    float* acc = smem;                 // NPB floats
    int* cl = (int*)(smem + NPB);      // NBLK ints
    int b = blockIdx.x;
    int tid = threadIdx.x;
    int nthr = blockDim.x;

    for (int i = tid; i < NPB; i += nthr) acc[i] = 0.f;
    for (int i = tid; i < NBLK; i += nthr) cl[i] = cnt[(size_t)b * NBLK + i];
    __syncthreads();

    size_t segBase = (size_t)b * NBLK * CAP;
    int total = NBLK * CAP;
    for (int idx = tid; idx < total; idx += nthr) {
        int blk = idx / CAP;           // CAP=32 -> shift
        int r = idx & (CAP - 1);
        if (r < cl[blk]) {
            int2 p = bucket[segBase + idx];
            atomicAdd(&acc[p.x], __int_as_float(p.y));
        }
    }
    __syncthreads();

    for (int i = tid; i < NPB; i += nthr) {
        int g = b * NPB + i;
        if (g < n) out[g] += acc[i];
    }
}

extern "C" void kernel_launch(void* const* d_in, const int* in_sizes, int n_in,
                              void* d_out, int out_size, void* d_ws, size_t ws_size,
                              hipStream_t stream) {
    const float* x      = (const float*)d_in[0];
    const int*   ei     = (const int*)d_in[1];
    const float* W_rel  = (const float*)d_in[2];
    const float* b_rel  = (const float*)d_in[3];
    const float* W_root = (const float*)d_in[4];
    float* out = (float*)d_out;

    int n = out_size;                 // N_NODES = 100000
    int E = in_sizes[1] / 2;          // 1200000

    int NB   = (n + NPB - 1) / NPB;          // 196 buckets
    int NBLK = (E + K2_EPB - 1) / K2_EPB;    // 293 bin blocks

    // ws layout: s [n floats] | cnt [NB*NBLK ints] | bucket [NB*NBLK*CAP int2]
    float* s = (float*)d_ws;
    size_t off = ((size_t)n * 4 + 15) & ~(size_t)15;
    int* cnt = (int*)((char*)d_ws + off);
    off += ((size_t)NB * NBLK * 4 + 15) & ~(size_t)15;
    int2* bucket = (int2*)((char*)d_ws + off);

    // 1) per-node scores + out init
    node_scores_kernel<<<(n + 15) / 16, 256, 0, stream>>>(
        (const float4*)x, (const float4*)W_rel, b_rel, (const float4*)W_root,
        s, out, n);

    // 2) bin edges by destination bucket
    size_t lds2 = (size_t)NB * sizeof(int);
    bin_kernel<<<NBLK, K2_THREADS, lds2, stream>>>(ei, s, out, cnt, bucket, E, NB, NBLK);

    // 3) per-bucket accumulate + out RMW
    size_t lds3 = (size_t)NPB * sizeof(float) + (size_t)NBLK * sizeof(int);
    gather_kernel<<<NB, 256, lds3, stream>>>(cnt, bucket, out, n, NBLK);
}

// Round 5
// 39.683 us; speedup vs baseline: 1.2502x; 1.2502x over previous
//
#include <hip/hip_runtime.h>

#define DIM 64
#define NPB 256           // nodes per bucket
#define NPB_SHIFT 8       // bin = dst >> 8
#define SEGCAP 4096       // pairs per bucket segment (mean fill ~3070)
#define K2_THREADS 512
#define K2_U 8
#define K2_EPB (K2_THREADS * K2_U)   // 4096 edges per bin-block

// Kernel 1: 16 threads per node row, float4 loads.
// s[i]   = dot(x[i], W_rel)
// out[i] = dot(x[i], W_root) + b_rel   (full overwrite -> replay-safe)
// Also zeroes the NB global cursors (gid < NB; K2 runs after K1 completes).
__global__ void node_scores_kernel(const float4* __restrict__ x4,
                                   const float4* __restrict__ Wrel4,
                                   const float* __restrict__ b_rel,
                                   const float4* __restrict__ Wroot4,
                                   float* __restrict__ s,
                                   float* __restrict__ out,
                                   int* __restrict__ cursor,
                                   int NB, int n) {
    int gid = blockIdx.x * blockDim.x + threadIdx.x;
    if (gid < NB) cursor[gid] = 0;

    int node = blockIdx.x * 16 + (threadIdx.x >> 4);
    int c = threadIdx.x & 15;
    if (node >= n) return;

    float4 xv = x4[(size_t)node * (DIM / 4) + c];
    float4 wr = Wrel4[c];
    float4 wt = Wroot4[c];
    float sr = xv.x * wr.x + xv.y * wr.y + xv.z * wr.z + xv.w * wr.w;
    float st = xv.x * wt.x + xv.y * wt.y + xv.z * wt.z + xv.w * wt.w;

    #pragma unroll
    for (int off = 1; off < 16; off <<= 1) {
        sr += __shfl_xor(sr, off);
        st += __shfl_xor(st, off);
    }
    if (c == 0) {
        s[node]   = sr;
        out[node] = st + b_rel[0];
    }
}

// Kernel 2: bucket-binning with exact global allocation + LDS compaction.
// Per block: histogram 4096 edges over NB bins (LDS atomics), reserve exact
// space in each bucket segment via one cursor atomicAdd per touched bin,
// compact pairs bin-ordered in LDS (Hillis-Steele scan), then copy out in
// runs of consecutive addresses (coalesced stores).
// Requires NB <= K2_THREADS.
__global__ __launch_bounds__(K2_THREADS)
void bin_kernel(const int* __restrict__ ei,
                const float* __restrict__ s,
                float* __restrict__ out,
                int* __restrict__ cursor,
                int2* __restrict__ bucket,
                int E, int NB) {
    __shared__ int2 lpair[K2_EPB];      // 32 KB
    __shared__ int  lga[K2_EPB];        // 16 KB
    __shared__ int  hist[K2_THREADS];   // 2 KB (later: exclusive base)
    __shared__ int  scan[K2_THREADS];   // 2 KB
    __shared__ int  start[K2_THREADS];  // 2 KB (global base per bin)

    int tid = threadIdx.x;
    int blk = blockIdx.x;
    hist[tid] = 0;
    __syncthreads();

    int base = blk * K2_EPB + tid * K2_U;
    int   dst[K2_U];
    float val[K2_U];
    int   rnk[K2_U];
    int   bin[K2_U];
    int   have = 0;

    if (base + K2_U <= E) {
        const int4* sv = (const int4*)ei;        // src row
        const int4* dv = (const int4*)(ei + E);  // dst row
        int g = base >> 2;
        int4 s0 = sv[g], s1 = sv[g + 1];
        int4 d0 = dv[g], d1 = dv[g + 1];
        dst[0] = d0.x; dst[1] = d0.y; dst[2] = d0.z; dst[3] = d0.w;
        dst[4] = d1.x; dst[5] = d1.y; dst[6] = d1.z; dst[7] = d1.w;
        val[0] = s[s0.x]; val[1] = s[s0.y]; val[2] = s[s0.z]; val[3] = s[s0.w];
        val[4] = s[s1.x]; val[5] = s[s1.y]; val[6] = s[s1.z]; val[7] = s[s1.w];
        have = K2_U;
    } else {
        #pragma unroll
        for (int k = 0; k < K2_U; ++k) {
            int e = base + k;
            if (e < E) {
                dst[k] = ei[E + e];
                val[k] = s[ei[e]];
                have = k + 1;
            }
        }
    }

    #pragma unroll
    for (int k = 0; k < K2_U; ++k) {
        if (k < have) {
            bin[k] = dst[k] >> NPB_SHIFT;
            rnk[k] = atomicAdd(&hist[bin[k]], 1);
        }
    }
    __syncthreads();

    // Exact global reservation (one same-address atomic per touched bin)
    int h = hist[tid];
    if (tid < NB && h > 0) start[tid] = atomicAdd(&cursor[tid], h);
    scan[tid] = h;
    __syncthreads();
    // Hillis-Steele inclusive scan over 512 lanes
    #pragma unroll
    for (int off = 1; off < K2_THREADS; off <<= 1) {
        int t = (tid >= off) ? scan[tid - off] : 0;
        __syncthreads();
        scan[tid] += t;
        __syncthreads();
    }
    hist[tid] = scan[tid] - h;   // exclusive base (LDS compaction offset)
    __syncthreads();

    int nE = min(K2_EPB, E - blk * K2_EPB);

    #pragma unroll
    for (int k = 0; k < K2_U; ++k) {
        if (k < have) {
            int b = bin[k];
            int slot = hist[b] + rnk[k];          // bin-ordered LDS slot
            int gofs = start[b] + rnk[k];         // offset within segment
            if (gofs < SEGCAP) {
                lpair[slot] = make_int2(dst[k] & (NPB - 1), __float_as_int(val[k]));
                lga[slot] = b * SEGCAP + gofs;
            } else {
                lga[slot] = -1;                   // overflow: direct fallback
                atomicAdd(&out[dst[k]], val[k]);
            }
        }
    }
    __syncthreads();

    // Coalesced copy-out: consecutive slots -> consecutive global addresses
    for (int i = tid; i < nE; i += K2_THREADS) {
        int ga = lga[i];
        if (ga >= 0) bucket[ga] = lpair[i];
    }
}

// Kernel 3: one block per bucket. Dense strip read, LDS accumulate,
// plain RMW of this bucket's disjoint out slice.
__global__ __launch_bounds__(NPB)
void gather_kernel(const int* __restrict__ cursor,
                   const int2* __restrict__ bucket,
                   float* __restrict__ out,
                   int n) {
    __shared__ float acc[NPB];
    int b = blockIdx.x;
    int tid = threadIdx.x;

    acc[tid] = 0.f;
    __syncthreads();

    int total = min(cursor[b], SEGCAP);
    const int2* seg = bucket + (size_t)b * SEGCAP;
    for (int i = tid; i < total; i += NPB) {
        int2 p = seg[i];
        atomicAdd(&acc[p.x], __int_as_float(p.y));
    }
    __syncthreads();

    int g = b * NPB + tid;
    if (g < n) out[g] += acc[tid];
}

extern "C" void kernel_launch(void* const* d_in, const int* in_sizes, int n_in,
                              void* d_out, int out_size, void* d_ws, size_t ws_size,
                              hipStream_t stream) {
    const float* x      = (const float*)d_in[0];
    const int*   ei     = (const int*)d_in[1];
    const float* W_rel  = (const float*)d_in[2];
    const float* b_rel  = (const float*)d_in[3];
    const float* W_root = (const float*)d_in[4];
    float* out = (float*)d_out;

    int n = out_size;                 // N_NODES = 100000
    int E = in_sizes[1] / 2;          // 1200000

    int NB = (n + NPB - 1) / NPB;     // 391 buckets (<= 512 required)

    // ws layout: s [n floats] | cursor [NB ints] | bucket [NB*SEGCAP int2]
    float* s = (float*)d_ws;
    size_t off = ((size_t)n * 4 + 255) & ~(size_t)255;
    int* cursor = (int*)((char*)d_ws + off);
    off += ((size_t)NB * 4 + 255) & ~(size_t)255;
    int2* bucket = (int2*)((char*)d_ws + off);

    // 1) per-node scores + out init + cursor zero
    node_scores_kernel<<<(n + 15) / 16, 256, 0, stream>>>(
        (const float4*)x, (const float4*)W_rel, b_rel, (const float4*)W_root,
        s, out, cursor, NB, n);

    // 2) bin edges into dense bucket segments
    int NBLK = (E + K2_EPB - 1) / K2_EPB;   // 293
    bin_kernel<<<NBLK, K2_THREADS, 0, stream>>>(ei, s, out, cursor, bucket, E, NB);

    // 3) per-bucket accumulate + disjoint out RMW
    gather_kernel<<<NB, NPB, 0, stream>>>(cursor, bucket, out, n);
}